// Round 4
// baseline (8494.559 us; speedup 1.0000x reference)
//
#include <hip/hip_runtime.h>

typedef unsigned int u32;
typedef unsigned long long u64;

// ---------------------------------------------------------------------------
// helpers
// ---------------------------------------------------------------------------
__device__ __forceinline__ u64 shflx64(u64 v, int m) {
  int lo = __shfl_xor((int)(u32)v, m, 64);
  int hi = __shfl_xor((int)(u32)(v >> 32), m, 64);
  return ((u64)(u32)hi << 32) | (u32)lo;
}
__device__ __forceinline__ u64 maxu64(u64 a, u64 b) { return a > b ? a : b; }

// merge two sorted-2 key lists (all keys distinct): (a1,a2) := top2(a1,a2,b1,b2)
__device__ __forceinline__ void merge2(u64& a1, u64& a2, u64 b1, u64 b2) {
  bool gt = a1 > b1;
  u64 n1 = gt ? a1 : b1;
  u64 n2 = gt ? maxu64(a2, b1) : maxu64(b2, a1);
  a1 = n1; a2 = n2;
}

// squared lower-bound distance from point c to an AABB
__device__ __forceinline__ float boxlb(float cx, float cy, float cz,
                                       float nx, float xx, float ny, float xy,
                                       float nz, float xz) {
  float gx = fmaxf(fmaxf(nx - cx, cx - xx), 0.0f);
  float gy = fmaxf(fmaxf(ny - cy, cy - xy), 0.0f);
  float gz = fmaxf(fmaxf(nz - cz, cz - xz), 0.0f);
  return gx * gx + gy * gy + gz * gz;
}

// ---------------------------------------------------------------------------
// Kernel 0: Morton sort. One block per batch; LDS bitonic sort of
// (morton18 << 14) | idx over N=16384 points (64 KB). Emits original indices
// in Morton order so k_fps threads/waves own compact spatial clusters.
// ---------------------------------------------------------------------------
#define SORT_T 1024

__global__ __launch_bounds__(SORT_T) void k_sort(const float* __restrict__ clouds,
                                                 u32* __restrict__ order, int N) {
  const int b = blockIdx.x, tid = threadIdx.x;
  const float* xs = clouds + (size_t)b * 4 * N;
  const float* ys = xs + N;
  const float* zs = ys + N;

  __shared__ u32 keys[16384];

  float mnx = 3.4e38f, mxx = -3.4e38f, mny = 3.4e38f, mxy = -3.4e38f,
        mnz = 3.4e38f, mxz = -3.4e38f;
  for (int i = tid; i < N; i += SORT_T) {
    float x = xs[i], y = ys[i], z = zs[i];
    mnx = fminf(mnx, x); mxx = fmaxf(mxx, x);
    mny = fminf(mny, y); mxy = fmaxf(mxy, y);
    mnz = fminf(mnz, z); mxz = fmaxf(mxz, z);
  }
#pragma unroll
  for (int s = 1; s < 64; s <<= 1) {
    mnx = fminf(mnx, __shfl_xor(mnx, s, 64)); mxx = fmaxf(mxx, __shfl_xor(mxx, s, 64));
    mny = fminf(mny, __shfl_xor(mny, s, 64)); mxy = fmaxf(mxy, __shfl_xor(mxy, s, 64));
    mnz = fminf(mnz, __shfl_xor(mnz, s, 64)); mxz = fmaxf(mxz, __shfl_xor(mxz, s, 64));
  }
  const int wv = tid >> 6;
  if ((tid & 63) == 0) {
    keys[wv * 6 + 0] = __float_as_uint(mnx); keys[wv * 6 + 1] = __float_as_uint(mxx);
    keys[wv * 6 + 2] = __float_as_uint(mny); keys[wv * 6 + 3] = __float_as_uint(mxy);
    keys[wv * 6 + 4] = __float_as_uint(mnz); keys[wv * 6 + 5] = __float_as_uint(mxz);
  }
  __syncthreads();
  float bmnx = __uint_as_float(keys[0]), bmxx = __uint_as_float(keys[1]);
  float bmny = __uint_as_float(keys[2]), bmxy = __uint_as_float(keys[3]);
  float bmnz = __uint_as_float(keys[4]), bmxz = __uint_as_float(keys[5]);
#pragma unroll
  for (int w = 1; w < 16; ++w) {
    bmnx = fminf(bmnx, __uint_as_float(keys[w * 6 + 0]));
    bmxx = fmaxf(bmxx, __uint_as_float(keys[w * 6 + 1]));
    bmny = fminf(bmny, __uint_as_float(keys[w * 6 + 2]));
    bmxy = fmaxf(bmxy, __uint_as_float(keys[w * 6 + 3]));
    bmnz = fminf(bmnz, __uint_as_float(keys[w * 6 + 4]));
    bmxz = fmaxf(bmxz, __uint_as_float(keys[w * 6 + 5]));
  }
  const float sx = 127.0f / fmaxf(bmxx - bmnx, 1e-9f);
  const float sy = 127.0f / fmaxf(bmxy - bmny, 1e-9f);
  const float sz = 15.0f / fmaxf(bmxz - bmnz, 1e-9f);
  __syncthreads();

  for (int i = tid; i < N; i += SORT_T) {
    int qx = min(127, max(0, (int)((xs[i] - bmnx) * sx)));
    int qy = min(127, max(0, (int)((ys[i] - bmny) * sy)));
    int qz = min(15, max(0, (int)((zs[i] - bmnz) * sz)));
    u32 m = 0; int sh = 0;
#pragma unroll
    for (int bit = 0; bit < 7; ++bit) {
      m |= ((u32)((qx >> bit) & 1)) << sh++;
      m |= ((u32)((qy >> bit) & 1)) << sh++;
      if (bit < 4) m |= ((u32)((qz >> bit) & 1)) << sh++;
    }
    keys[i] = (m << 14) | (u32)i;
  }
  __syncthreads();

  for (int k = 2; k <= 16384; k <<= 1) {
    for (int j = k >> 1; j > 0; j >>= 1) {
      for (int t = tid; t < 16384; t += SORT_T) {
        int ixj = t ^ j;
        if (ixj > t) {
          u32 a = keys[t], c = keys[ixj];
          bool up = ((t & k) == 0);
          if ((a > c) == up) { keys[t] = c; keys[ixj] = a; }
        }
      }
      __syncthreads();
    }
  }
  for (int i = tid; i < N; i += SORT_T)
    order[(size_t)b * N + i] = keys[i] & 0x3FFFu;
}

// ---------------------------------------------------------------------------
// Kernel 1: exact FPS with Morton clustering, bbox pruning, ONE barrier per
// round, and exact DOUBLE-PICK: block-reduce carries the exact top-2 keys
// (key = ddbits<<32 | ~orig_idx == numpy argmax-first-occurrence order).
// After picking w1, if d^2(w2,w1) >= m2 (computed with the reference's _rn
// op sequence), then w2 is provably the next pick (dd' <= m2 everywhere,
// dd'[w2] = m2, tie order preserved) -- two picks per barrier round.
// The next round then min-updates against both centers (bitwise identical
// to two sequential updates). Skips are exact: a center is skipped for a
// wave/thread only when its bbox lower bound guarantees d >= dd for all
// owned points (1e-5 rel margin >> fp32 rounding), leaving dd bit-identical.
// ---------------------------------------------------------------------------
#define FPS_T 1024

__global__ __launch_bounds__(FPS_T, 4) void k_fps(const float* __restrict__ clouds,
                                                  const u32* __restrict__ order,
                                                  float* __restrict__ keyp,
                                                  int N, int K) {
  const int b = blockIdx.x, tid = threadIdx.x;
  const float* xs = clouds + (size_t)b * 4 * N;
  const float* ys = xs + N;
  const float* zs = ys + N;

  // oid packed 2 x u16 per reg (indices < 16384)
  u32 op[8];
  float px[16], py[16], pz[16], dd[16];
#pragma unroll
  for (int j = 0; j < 8; ++j) {
    u32 lo = order[(size_t)b * N + tid * 16 + 2 * j];
    u32 hi = order[(size_t)b * N + tid * 16 + 2 * j + 1];
    op[j] = lo | (hi << 16);
  }
#pragma unroll
  for (int j = 0; j < 16; ++j) {
    u32 oj = (op[j >> 1] >> ((j & 1) * 16)) & 0xFFFFu;
    px[j] = xs[oj]; py[j] = ys[oj]; pz[j] = zs[oj];
    dd[j] = 1e10f;
  }
  // thread bbox
  float bnx = px[0], bxx = px[0], bny = py[0], bxy = py[0], bnz = pz[0], bxz = pz[0];
#pragma unroll
  for (int j = 1; j < 16; ++j) {
    bnx = fminf(bnx, px[j]); bxx = fmaxf(bxx, px[j]);
    bny = fminf(bny, py[j]); bxy = fmaxf(bxy, py[j]);
    bnz = fminf(bnz, pz[j]); bxz = fmaxf(bxz, pz[j]);
  }
  // wave bbox
  float wnx = bnx, wxx = bxx, wny = bny, wxy = bxy, wnz = bnz, wxz = bxz;
#pragma unroll
  for (int s = 1; s < 64; s <<= 1) {
    wnx = fminf(wnx, __shfl_xor(wnx, s, 64)); wxx = fmaxf(wxx, __shfl_xor(wxx, s, 64));
    wny = fminf(wny, __shfl_xor(wny, s, 64)); wxy = fmaxf(wxy, __shfl_xor(wxy, s, 64));
    wnz = fminf(wnz, __shfl_xor(wnz, s, 64)); wxz = fmaxf(wxz, __shfl_xor(wxz, s, 64));
  }

  __shared__ u64 sl1[2][16], sl2[2][16];
  const int wv = tid >> 6, ln = tid & 63;

  const u64 initk = ((u64)__float_as_uint(1e10f)) << 32;
  u64 tk1 = initk, tk2 = initk;      // thread top-2 (persistent)
  u64 wk1 = initk, wk2 = initk;      // wave top-2 (persistent)
  float wmax = 1e10f;

  float c1x = xs[0], c1y = ys[0], c1z = zs[0];   // pending centers
  float c2x = 0.f, c2y = 0.f, c2z = 0.f;
  bool has2 = false;

  if (tid == 0) {
    float* kb = keyp + (size_t)b * K * 3;
    kb[0] = c1x; kb[1] = c1y; kb[2] = c1z;
  }

  int t = 1, rnd = 0;
  while (t < K) {
    const int par = rnd & 1; ++rnd;
    // wave-level per-center prune (uniform)
    bool u1w = boxlb(c1x, c1y, c1z, wnx, wxx, wny, wxy, wnz, wxz)
               <= wmax * 1.00001f;
    bool u2w = has2 && (boxlb(c2x, c2y, c2z, wnx, wxx, wny, wxy, wnz, wxz)
                        <= wmax * 1.00001f);
    if (u1w || u2w) {
      float tmax = __uint_as_float((u32)(tk1 >> 32));
      bool u1t = u1w && (boxlb(c1x, c1y, c1z, bnx, bxx, bny, bxy, bnz, bxz)
                         <= tmax * 1.00001f);
      bool u2t = u2w && (boxlb(c2x, c2y, c2z, bnx, bxx, bny, bxy, bnz, bxz)
                         <= tmax * 1.00001f);
      if (u1t || u2t) {
        float m1 = 0.0f, m2 = 0.0f;
#pragma unroll
        for (int j = 0; j < 16; ++j) {
          float dn = dd[j];
          if (u1t) {
            float dx = __fsub_rn(px[j], c1x), dy = __fsub_rn(py[j], c1y),
                  dz = __fsub_rn(pz[j], c1z);
            float d = __fadd_rn(__fadd_rn(__fmul_rn(dx, dx), __fmul_rn(dy, dy)),
                                __fmul_rn(dz, dz));
            dn = fminf(dn, d);
          }
          if (u2t) {
            float dx = __fsub_rn(px[j], c2x), dy = __fsub_rn(py[j], c2y),
                  dz = __fsub_rn(pz[j], c2z);
            float d = __fadd_rn(__fadd_rn(__fmul_rn(dx, dx), __fmul_rn(dy, dy)),
                                __fmul_rn(dz, dz));
            dn = fminf(dn, d);
          }
          dd[j] = dn;
          m2 = fmaxf(m2, fminf(m1, dn));
          m1 = fmaxf(m1, dn);
        }
        // resolve exact first-occurrence indices for m1 and the 2nd place
        u32 mi1 = 0xFFFFFFFFu;
#pragma unroll
        for (int j = 0; j < 16; ++j) {
          u32 oj = (op[j >> 1] >> ((j & 1) * 16)) & 0xFFFFu;
          if (dd[j] == m1) mi1 = min(mi1, oj);
        }
        bool tie = (m2 == m1);
        u32 mi2 = 0xFFFFFFFFu;
#pragma unroll
        for (int j = 0; j < 16; ++j) {
          u32 oj = (op[j >> 1] >> ((j & 1) * 16)) & 0xFFFFu;
          bool sel = tie ? (dd[j] == m1 && oj != mi1) : (dd[j] == m2);
          if (sel) mi2 = min(mi2, oj);
        }
        tk1 = (((u64)__float_as_uint(m1)) << 32) | (u64)(u32)(~mi1);
        tk2 = (((u64)__float_as_uint(m2)) << 32) | (u64)(u32)(~mi2);
      }
      // wave butterfly: merge sorted-2 key lists
      u64 a1 = tk1, a2 = tk2;
#pragma unroll
      for (int s = 1; s < 64; s <<= 1) {
        u64 b1 = shflx64(a1, s), b2 = shflx64(a2, s);
        merge2(a1, a2, b1, b2);
      }
      wk1 = a1; wk2 = a2;
      wmax = __uint_as_float((u32)(wk1 >> 32));
    }
    if (ln == 0) { sl1[par][wv] = wk1; sl2[par][wv] = wk2; }
    __syncthreads();
    // block butterfly over 16 wave slots (replicated across lane groups)
    u64 a1 = sl1[par][ln & 15], a2 = sl2[par][ln & 15];
#pragma unroll
    for (int s = 1; s < 16; s <<= 1) {
      u64 b1 = shflx64(a1, s), b2 = shflx64(a2, s);
      merge2(a1, a2, b1, b2);
    }
    const u32 gi1 = ~(u32)a1;
    const u32 gi2 = ~(u32)a2;
    const float m2f = __uint_as_float((u32)(a2 >> 32));
    // winner coords (broadcast loads, both candidates in parallel)
    float nx1 = xs[gi1], ny1 = ys[gi1], nz1 = zs[gi1];
    float nx2 = xs[gi2], ny2 = ys[gi2], nz2 = zs[gi2];
    // exact double-pick test: d^2(w2,w1) >= m2 with reference rounding
    float ex = __fsub_rn(nx2, nx1), ey = __fsub_rn(ny2, ny1),
          ez = __fsub_rn(nz2, nz1);
    float d12 = __fadd_rn(__fadd_rn(__fmul_rn(ex, ex), __fmul_rn(ey, ey)),
                          __fmul_rn(ez, ez));
    bool take2 = (t + 1 < K) && (d12 >= m2f);
    if (tid == 0) {
      float* kb = keyp + ((size_t)b * K + t) * 3;
      kb[0] = nx1; kb[1] = ny1; kb[2] = nz1;
      if (take2) { kb[3] = nx2; kb[4] = ny2; kb[5] = nz2; }
    }
    c1x = nx1; c1y = ny1; c1z = nz1;
    c2x = nx2; c2y = ny2; c2z = nz2;
    has2 = take2;
    t += take2 ? 2 : 1;
  }
}

// ---------------------------------------------------------------------------
// Kernel 2: per-keypoint candidate collection (d2 < r_b^2) + exact rank
// selection of the 32 nearest, ordered by (d2, idx). Slot = (d2bits<<32)|idx;
// sentinel = FLT_MAX bits. Also writes keypoint coords into d_out.
// ---------------------------------------------------------------------------
#define KNN_T 256
#define KNN_CAP 1024
#define SENTINEL (((u64)0x7F7FFFFFu) << 32)

__global__ __launch_bounds__(KNN_T) void k_knn(const float* __restrict__ clouds,
                                               const float* __restrict__ keyp,
                                               u64* __restrict__ slots,
                                               float* __restrict__ out,
                                               int N, int K, float r2b) {
  const int kp = blockIdx.x;
  const int b = kp / K;
  const int tid = threadIdx.x;
  const float* xs = clouds + (size_t)b * 4 * N;
  const float* ys = xs + N;
  const float* zs = ys + N;

  __shared__ u64 cand[KNN_CAP];
  __shared__ int cnt;
  __shared__ u64 sorted32[32];

  if (tid == 0) cnt = 0;
  if (tid < 32) sorted32[tid] = SENTINEL;
  const float kx = keyp[(size_t)kp * 3 + 0];
  const float ky = keyp[(size_t)kp * 3 + 1];
  const float kz = keyp[(size_t)kp * 3 + 2];
  __syncthreads();

  for (int i = tid; i < N; i += KNN_T) {
    float dx = __fsub_rn(xs[i], kx), dy = __fsub_rn(ys[i], ky),
          dz = __fsub_rn(zs[i], kz);
    float d = __fadd_rn(__fadd_rn(__fmul_rn(dx, dx), __fmul_rn(dy, dy)),
                        __fmul_rn(dz, dz));
    if (d < r2b) {
      int p = atomicAdd(&cnt, 1);
      if (p < KNN_CAP)
        cand[p] = (((u64)__float_as_uint(d)) << 32) | (u64)(u32)i;
    }
  }
  __syncthreads();
  int n = min(cnt, KNN_CAP);
  for (int i = tid; i < n; i += KNN_T) {
    u64 kk = cand[i];
    int r = 0;
    for (int j = 0; j < n; ++j) r += (cand[j] < kk) ? 1 : 0;
    if (r < 32) sorted32[r] = kk;
  }
  __syncthreads();
  if (tid < 32) slots[(size_t)kp * 32 + tid] = sorted32[tid];
  if (tid < 3) out[(size_t)kp * 131 + tid] = keyp[(size_t)kp * 3 + tid];
}

// ---------------------------------------------------------------------------
// Kernel 3: per-keypoint PointNet layer1 (4->128) + layer2 (128->256) +
// masked max-pool, fp32. One block per keypoint; W2 staged in 32-row k-tiles.
// ---------------------------------------------------------------------------
template <int M>
__global__ __launch_bounds__(256) void k_pool(const float* __restrict__ clouds,
                                              const float* __restrict__ keyp,
                                              const u64* __restrict__ slots,
                                              const float* __restrict__ w1,
                                              const float* __restrict__ w2,
                                              float* __restrict__ pooled,
                                              int N, int K, float R2, int colOff) {
  constexpr int R = M / 4;
  const int kp = blockIdx.x;
  const int b = kp / K;
  const int tid = threadIdx.x;
  const float* xs = clouds + (size_t)b * 4 * N;
  const float* ys = xs + N;
  const float* zs = ys + N;
  const float* fs = zs + N;

  __shared__ float w1l[512];
  __shared__ float gx[32], gy[32], gz[32], gf[32];
  __shared__ float h1l[32 * 132];
  __shared__ float w2l[32 * 256];
  __shared__ u32 pm[256];

  const float kx = keyp[(size_t)kp * 3 + 0];
  const float ky = keyp[(size_t)kp * 3 + 1];
  const float kz = keyp[(size_t)kp * 3 + 2];

  w1l[tid] = w1[tid];
  w1l[tid + 256] = w1[tid + 256];
  pm[tid] = 0u;
  if (tid < M) {
    u64 sl = slots[(size_t)kp * 32 + tid];
    float d2 = __uint_as_float((u32)(sl >> 32));
    u32 idx = (u32)sl;
    float vx = 0.f, vy = 0.f, vz = 0.f, vf = 0.f;
    if (d2 < R2) {
      vx = xs[idx] - kx;
      vy = ys[idx] - ky;
      vz = zs[idx] - kz;
      vf = fs[idx];
    }
    gx[tid] = vx; gy[tid] = vy; gz[tid] = vz; gf[tid] = vf;
  }
  __syncthreads();

  {
    const int c = tid & 127;
#pragma unroll
    for (int p = 0; p < M / 2; ++p) {
      int r = p * 2 + (tid >> 7);
      float h = fmaf(gf[r], w1l[384 + c],
                fmaf(gz[r], w1l[256 + c],
                fmaf(gy[r], w1l[128 + c], gx[r] * w1l[c])));
      h1l[r * 132 + c] = fmaxf(h, 0.0f);
    }
  }

  const int rt = tid >> 6;
  const int cg = tid & 63;
  float acc[R][4];
#pragma unroll
  for (int rr = 0; rr < R; ++rr)
#pragma unroll
    for (int cc = 0; cc < 4; ++cc) acc[rr][cc] = 0.0f;

  for (int kt = 0; kt < 4; ++kt) {
    __syncthreads();
    for (int q = tid; q < 32 * 256; q += 256)
      w2l[q] = w2[(size_t)(kt * 32 + (q >> 8)) * 256 + (q & 255)];
    __syncthreads();
    for (int k = 0; k < 32; k += 4) {
      float4 hv[R];
#pragma unroll
      for (int rr = 0; rr < R; ++rr)
        hv[rr] = *reinterpret_cast<const float4*>(
            &h1l[(rt * R + rr) * 132 + kt * 32 + k]);
      float4 wv[4];
#pragma unroll
      for (int kk = 0; kk < 4; ++kk)
        wv[kk] = *reinterpret_cast<const float4*>(
            &w2l[(k + kk) * 256 + cg * 4]);
#pragma unroll
      for (int rr = 0; rr < R; ++rr) {
        const float a0 = hv[rr].x, a1 = hv[rr].y, a2 = hv[rr].z, a3 = hv[rr].w;
        acc[rr][0] = fmaf(a3, wv[3].x, fmaf(a2, wv[2].x,
                     fmaf(a1, wv[1].x, fmaf(a0, wv[0].x, acc[rr][0]))));
        acc[rr][1] = fmaf(a3, wv[3].y, fmaf(a2, wv[2].y,
                     fmaf(a1, wv[1].y, fmaf(a0, wv[0].y, acc[rr][1]))));
        acc[rr][2] = fmaf(a3, wv[3].z, fmaf(a2, wv[2].z,
                     fmaf(a1, wv[1].z, fmaf(a0, wv[0].z, acc[rr][2]))));
        acc[rr][3] = fmaf(a3, wv[3].w, fmaf(a2, wv[2].w,
                     fmaf(a1, wv[1].w, fmaf(a0, wv[0].w, acc[rr][3]))));
      }
    }
  }
#pragma unroll
  for (int cc = 0; cc < 4; ++cc) {
    float mx = 0.0f;
#pragma unroll
    for (int rr = 0; rr < R; ++rr) mx = fmaxf(mx, acc[rr][cc]);
    atomicMax(&pm[cg * 4 + cc], __float_as_uint(mx));
  }
  __syncthreads();
  pooled[(size_t)kp * 512 + colOff + tid] = __uint_as_float(pm[tid]);
}

// ---------------------------------------------------------------------------
// Kernel 4: fuse GEMM [BK,512]@[512,128] + relu -> d_out features (fp32).
// ---------------------------------------------------------------------------
__global__ __launch_bounds__(256) void k_fuse(const float* __restrict__ pooled,
                                              const float* __restrict__ wf,
                                              float* __restrict__ out) {
  const int m0 = blockIdx.x * 16;
  const int tid = threadIdx.x;
  __shared__ float al[16 * 516];
  __shared__ float wl[32 * 128];

  for (int q = tid; q < 16 * 512; q += 256)
    al[(q >> 9) * 516 + (q & 511)] =
        pooled[(size_t)(m0 + (q >> 9)) * 512 + (q & 511)];

  const int rg = tid >> 5;
  const int cg = tid & 31;
  float acc[2][4];
#pragma unroll
  for (int rr = 0; rr < 2; ++rr)
#pragma unroll
    for (int cc = 0; cc < 4; ++cc) acc[rr][cc] = 0.0f;

  for (int kt = 0; kt < 16; ++kt) {
    __syncthreads();
    for (int q = tid; q < 32 * 128; q += 256)
      wl[q] = wf[(size_t)(kt * 32 + (q >> 7)) * 128 + (q & 127)];
    __syncthreads();
    for (int k = 0; k < 32; k += 4) {
      float4 av[2];
#pragma unroll
      for (int rr = 0; rr < 2; ++rr)
        av[rr] = *reinterpret_cast<const float4*>(
            &al[(rg * 2 + rr) * 516 + kt * 32 + k]);
      float4 wv[4];
#pragma unroll
      for (int kk = 0; kk < 4; ++kk)
        wv[kk] = *reinterpret_cast<const float4*>(&wl[(k + kk) * 128 + cg * 4]);
#pragma unroll
      for (int rr = 0; rr < 2; ++rr) {
        const float a0 = av[rr].x, a1 = av[rr].y, a2 = av[rr].z, a3 = av[rr].w;
        acc[rr][0] = fmaf(a3, wv[3].x, fmaf(a2, wv[2].x,
                     fmaf(a1, wv[1].x, fmaf(a0, wv[0].x, acc[rr][0]))));
        acc[rr][1] = fmaf(a3, wv[3].y, fmaf(a2, wv[2].y,
                     fmaf(a1, wv[1].y, fmaf(a0, wv[0].y, acc[rr][1]))));
        acc[rr][2] = fmaf(a3, wv[3].z, fmaf(a2, wv[2].z,
                     fmaf(a1, wv[1].z, fmaf(a0, wv[0].z, acc[rr][2]))));
        acc[rr][3] = fmaf(a3, wv[3].w, fmaf(a2, wv[2].w,
                     fmaf(a1, wv[1].w, fmaf(a0, wv[0].w, acc[rr][3]))));
      }
    }
  }
#pragma unroll
  for (int rr = 0; rr < 2; ++rr) {
    const size_t row = (size_t)(m0 + rg * 2 + rr);
#pragma unroll
    for (int cc = 0; cc < 4; ++cc)
      out[row * 131 + 3 + cg * 4 + cc] = fmaxf(acc[rr][cc], 0.0f);
  }
}

// ---------------------------------------------------------------------------
extern "C" void kernel_launch(void* const* d_in, const int* in_sizes, int n_in,
                              void* d_out, int out_size, void* d_ws, size_t ws_size,
                              hipStream_t stream) {
  const float* clouds = (const float*)d_in[0];
  const float* w1a = (const float*)d_in[1];
  const float* w2a = (const float*)d_in[2];
  const float* w1b = (const float*)d_in[3];
  const float* w2b = (const float*)d_in[4];
  const float* wfu = (const float*)d_in[5];
  float* out = (float*)d_out;

  const int B = 2;
  const int N = in_sizes[0] / (4 * B);  // 16384
  const int K = out_size / (131 * B);   // 4096
  const int BK = B * K;                 // 8192

  char* ws = (char*)d_ws;
  u32* order = (u32*)ws;                                  // B*N u32
  size_t off = ((size_t)B * N * sizeof(u32) + 255) & ~(size_t)255;
  float* keyp = (float*)(ws + off);                       // BK*3 f32
  off += (size_t)BK * 3 * sizeof(float);
  off = (off + 255) & ~(size_t)255;
  u64* slots = (u64*)(ws + off);                          // BK*32 u64
  off += (size_t)BK * 32 * sizeof(u64);
  off = (off + 255) & ~(size_t)255;
  float* pooled = (float*)(ws + off);                     // BK*512 f32

  const float r2a = (float)(0.8 * 0.8);
  const float r2b = (float)(1.6 * 1.6);

  k_sort<<<dim3(B), dim3(SORT_T), 0, stream>>>(clouds, order, N);
  k_fps<<<dim3(B), dim3(FPS_T), 0, stream>>>(clouds, order, keyp, N, K);
  k_knn<<<dim3(BK), dim3(KNN_T), 0, stream>>>(clouds, keyp, slots, out, N, K, r2b);
  k_pool<16><<<dim3(BK), dim3(256), 0, stream>>>(clouds, keyp, slots, w1a, w2a,
                                                 pooled, N, K, r2a, 0);
  k_pool<32><<<dim3(BK), dim3(256), 0, stream>>>(clouds, keyp, slots, w1b, w2b,
                                                 pooled, N, K, r2b, 256);
  k_fuse<<<dim3(BK / 16), dim3(256), 0, stream>>>(pooled, wfu, out);
}